// Round 1
// baseline (250.992 us; speedup 1.0000x reference)
//
#include <hip/hip_runtime.h>
#include <hip/hip_bf16.h>

#define N_NODES 10000
#define N_EDGES 100000

typedef __attribute__((ext_vector_type(8))) short short8;
typedef __attribute__((ext_vector_type(4))) float f32x4;

// float -> bf16 bits (RNE via compiler __bf16 conversion)
static __device__ inline short bf16bits(float x) {
    union { __bf16 b; short s; } u;
    u.b = (__bf16)x;
    return u.s;
}

static __device__ inline short8 cvt8(const float* f) {
    short8 r;
#pragma unroll
    for (int j = 0; j < 8; ++j) r[j] = bf16bits(f[j]);
    return r;
}

// ---------------------------------------------------------------------------
// Precompute: fold L1s/L1v into Wgen (bf16, MFMA B-fragment order) and
// L2s/L2v into WS0/WS1 (f32, [k][w] layout).
// Edge combined scale: rnorm*alpha*lnorm = (1/sqrt8)(1/8)(1/sqrt32) = 1/128.
// Node combined scale: snorm*lnorm = (1/sqrt512)(1/sqrt32) = 1/128.
// ---------------------------------------------------------------------------
__global__ __launch_bounds__(256) void prep_kernel(
    const float* __restrict__ Wgen, const float* __restrict__ L1s,
    const float* __restrict__ L1v, const float* __restrict__ WS0,
    const float* __restrict__ WS1, const float* __restrict__ L2s,
    const float* __restrict__ L2v, unsigned short* __restrict__ Wc,
    float* __restrict__ WS0p, float* __restrict__ WS1p) {
    const float S = 1.0f / 128.0f;
    int tid = blockIdx.x * 256 + threadIdx.x;
    if (tid < 32768) {
        // Edge weights in B-fragment order:
        // flat = ((nt*8 + ks)*64 + lane)*8 + j
        // col = nt*16 + (lane&15); k = ks*32 + (lane>>4)*8 + j -> r=ks, u=k%32
        int j = tid & 7;
        int lane = (tid >> 3) & 63;
        int ks = (tid >> 9) & 7;
        int nt = tid >> 12;
        int col = nt * 16 + (lane & 15);
        int u = (lane >> 4) * 8 + j;
        int r = ks;
        int p, c2;
        const float* M;
        float sc = S;
        if (col < 32)      { p = 0; M = L1s; c2 = col; }
        else if (col < 64) { p = 1; M = L1v; c2 = col - 32; }
        else if (col < 96) { p = 2; M = L1v; c2 = col - 64; }
        else               { p = 3; M = L1s; c2 = col - 96; sc = S * 0.57735026918962576f; }
        const float* wg = Wgen + r * 4096 + p * 1024 + u * 32;
        float acc = 0.f;
#pragma unroll
        for (int w = 0; w < 32; ++w) acc += wg[w] * M[w * 32 + c2];
        union { __bf16 b; unsigned short s; } cv;
        cv.b = (__bf16)(acc * sc);
        Wc[tid] = cv.s;
    } else if (tid < 65536) {
        int idx = tid - 32768;
        int path = idx >> 14;        // 0: WS0@L2s, 1: WS1@L2v
        int idx2 = idx & 16383;      // k*32 + w
        int k = idx2 >> 5;
        int w = idx2 & 31;
        int u = k >> 4, v = k & 15;
        const float* WS = path ? WS1 : WS0;
        const float* L2 = path ? L2v : L2s;
        const float* src = WS + u * 512 + v * 32;
        float acc = 0.f;
#pragma unroll
        for (int x = 0; x < 32; ++x) acc += src[x] * L2[x * 32 + w];
        float val = acc * S;
        if (path) WS1p[idx2] = val; else WS0p[idx2] = val;
    }
}

// ---------------------------------------------------------------------------
// Edge kernel: per 16-edge tile (one wave), MFMA over K=256:
//   fA = (ef(x)xs)@A', fB = (ef(x)xs)@B', fC_i = (ef(x)xv_i)@C', fD = (ef(x)dot)@D'
//   ms' = ys*fA + fD ; mv'[u,i] = yv_i*fB + ys*fC_i ; atomicAdd into Ms/Mv.
// ---------------------------------------------------------------------------
__global__ __launch_bounds__(256) void edge_kernel(
    const float* __restrict__ node_feats, const float* __restrict__ edge_attrs,
    const float* __restrict__ edge_feats, const int* __restrict__ edge_index,
    const unsigned short* __restrict__ Wc, float* __restrict__ Ms,
    float* __restrict__ Mv) {
    __shared__ f32x4 sWv[4096];  // 64KB: bf16 weights in fragment order
    {
        const f32x4* src = (const f32x4*)Wc;
        for (int i = threadIdx.x; i < 4096; i += 256) sWv[i] = src[i];
    }
    __syncthreads();
    const short8* sW8 = (const short8*)sWv;

    int lane = threadIdx.x & 63;
    int m = lane & 15, q = lane >> 4;
    int wave = (blockIdx.x * 256 + threadIdx.x) >> 6;
    int nwaves = gridDim.x * 4;

    for (int tile = wave; tile < N_EDGES / 16; tile += nwaves) {
        int e = tile * 16 + m;
        int snd = edge_index[e];
        int rcv = edge_index[N_EDGES + e];
        const float* g = node_feats + snd * 128;

        float xs[8], xv[24], ef[8], dt[8];
        *(f32x4*)&xs[0] = *(const f32x4*)(g + q * 8);
        *(f32x4*)&xs[4] = *(const f32x4*)(g + q * 8 + 4);
#pragma unroll
        for (int i = 0; i < 6; ++i)
            *(f32x4*)&xv[i * 4] = *(const f32x4*)(g + 32 + q * 24 + i * 4);
        *(f32x4*)&ef[0] = *(const f32x4*)(edge_feats + e * 8);
        *(f32x4*)&ef[4] = *(const f32x4*)(edge_feats + e * 8 + 4);
        f32x4 ea = *(const f32x4*)(edge_attrs + e * 4);
        float ys = ea.x, yv0 = ea.y, yv1 = ea.z, yv2 = ea.w;
#pragma unroll
        for (int j = 0; j < 8; ++j)
            dt[j] = xv[j * 3] * yv0 + xv[j * 3 + 1] * yv1 + xv[j * 3 + 2] * yv2;

        f32x4 z = {0.f, 0.f, 0.f, 0.f};
        f32x4 fA[2] = {z, z}, fB[2] = {z, z}, fD[2] = {z, z};
        f32x4 fC[3][2] = {{z, z}, {z, z}, {z, z}};

#pragma unroll
        for (int ks = 0; ks < 8; ++ks) {
            float h = ef[ks];
            float t0[8], t1[8], t2[8], t3[8], t4[8];
#pragma unroll
            for (int j = 0; j < 8; ++j) {
                t0[j] = h * xs[j];
                t1[j] = h * xv[j * 3 + 0];
                t2[j] = h * xv[j * 3 + 1];
                t3[j] = h * xv[j * 3 + 2];
                t4[j] = h * dt[j];
            }
            short8 a_xs = cvt8(t0);
            short8 a_v0 = cvt8(t1);
            short8 a_v1 = cvt8(t2);
            short8 a_v2 = cvt8(t3);
            short8 a_d  = cvt8(t4);
#define BFRAG(nt) sW8[((nt) * 8 + ks) * 64 + lane]
            fA[0] = __builtin_amdgcn_mfma_f32_16x16x32_bf16(a_xs, BFRAG(0), fA[0], 0, 0, 0);
            fA[1] = __builtin_amdgcn_mfma_f32_16x16x32_bf16(a_xs, BFRAG(1), fA[1], 0, 0, 0);
            fB[0] = __builtin_amdgcn_mfma_f32_16x16x32_bf16(a_xs, BFRAG(2), fB[0], 0, 0, 0);
            fB[1] = __builtin_amdgcn_mfma_f32_16x16x32_bf16(a_xs, BFRAG(3), fB[1], 0, 0, 0);
            short8 bc0 = BFRAG(4), bc1 = BFRAG(5);
            fC[0][0] = __builtin_amdgcn_mfma_f32_16x16x32_bf16(a_v0, bc0, fC[0][0], 0, 0, 0);
            fC[0][1] = __builtin_amdgcn_mfma_f32_16x16x32_bf16(a_v0, bc1, fC[0][1], 0, 0, 0);
            fC[1][0] = __builtin_amdgcn_mfma_f32_16x16x32_bf16(a_v1, bc0, fC[1][0], 0, 0, 0);
            fC[1][1] = __builtin_amdgcn_mfma_f32_16x16x32_bf16(a_v1, bc1, fC[1][1], 0, 0, 0);
            fC[2][0] = __builtin_amdgcn_mfma_f32_16x16x32_bf16(a_v2, bc0, fC[2][0], 0, 0, 0);
            fC[2][1] = __builtin_amdgcn_mfma_f32_16x16x32_bf16(a_v2, bc1, fC[2][1], 0, 0, 0);
            fD[0] = __builtin_amdgcn_mfma_f32_16x16x32_bf16(a_d, BFRAG(6), fD[0], 0, 0, 0);
            fD[1] = __builtin_amdgcn_mfma_f32_16x16x32_bf16(a_d, BFRAG(7), fD[1], 0, 0, 0);
#undef BFRAG
        }

        // Epilogue: D-frag row = q*4+t (edge), col = m (+16*nt)
#pragma unroll
        for (int t = 0; t < 4; ++t) {
            int row = q * 4 + t;
            float ysr = __shfl(ys, row);
            float y0r = __shfl(yv0, row);
            float y1r = __shfl(yv1, row);
            float y2r = __shfl(yv2, row);
            int rr = __shfl(rcv, row);
#pragma unroll
            for (int nt = 0; nt < 2; ++nt) {
                int col = nt * 16 + m;
                unsafeAtomicAdd(&Ms[rr * 32 + col], ysr * fA[nt][t] + fD[nt][t]);
                float pb = fB[nt][t];
                unsafeAtomicAdd(&Mv[rr * 96 + col * 3 + 0], y0r * pb + ysr * fC[0][nt][t]);
                unsafeAtomicAdd(&Mv[rr * 96 + col * 3 + 1], y1r * pb + ysr * fC[1][nt][t]);
                unsafeAtomicAdd(&Mv[rr * 96 + col * 3 + 2], y2r * pb + ysr * fC[2][nt][t]);
            }
        }
    }
}

// ---------------------------------------------------------------------------
// Node kernel: out_s[n,w] = Ms[n,w] + sum_k (Ms[n,u]*attr[n,v]) * WS0p[k,w]
//              out_v[n,w,i] = Mv[n,w,i] + sum_k (Mv[n,u,i]*attr[n,v]) * WS1p[k,w]
// 8 nodes per block, 32 lanes per node.
// ---------------------------------------------------------------------------
__global__ __launch_bounds__(256) void node_kernel(
    const float* __restrict__ node_attrs, const float* __restrict__ Ms,
    const float* __restrict__ Mv, const float* __restrict__ WS0p,
    const float* __restrict__ WS1p, float* __restrict__ out) {
    __shared__ float sMs[8][32], sMv[8][96], sAt[8][16];
    int slot = threadIdx.x >> 5, w = threadIdx.x & 31;
    int n = blockIdx.x * 8 + slot;
    sMs[slot][w] = Ms[n * 32 + w];
    sMv[slot][w] = Mv[n * 96 + w];
    sMv[slot][32 + w] = Mv[n * 96 + 32 + w];
    sMv[slot][64 + w] = Mv[n * 96 + 64 + w];
    if (w < 16) sAt[slot][w] = node_attrs[n * 16 + w];
    __syncthreads();

    float ss = 0.f, sv0 = 0.f, sv1 = 0.f, sv2 = 0.f;
    for (int u = 0; u < 32; ++u) {
        float msu = sMs[slot][u];
        float m0 = sMv[slot][u * 3 + 0];
        float m1 = sMv[slot][u * 3 + 1];
        float m2 = sMv[slot][u * 3 + 2];
        const float* w0p = WS0p + u * 512 + w;
        const float* w1p = WS1p + u * 512 + w;
#pragma unroll
        for (int v = 0; v < 16; ++v) {
            float av = sAt[slot][v];
            float wt0 = w0p[v * 32];
            float wt1 = w1p[v * 32];
            ss  += (msu * av) * wt0;
            sv0 += (m0 * av) * wt1;
            sv1 += (m1 * av) * wt1;
            sv2 += (m2 * av) * wt1;
        }
    }
    out[n * 128 + w] = sMs[slot][w] + ss;
    out[n * 128 + 32 + w * 3 + 0] = sMv[slot][w * 3 + 0] + sv0;
    out[n * 128 + 32 + w * 3 + 1] = sMv[slot][w * 3 + 1] + sv1;
    out[n * 128 + 32 + w * 3 + 2] = sMv[slot][w * 3 + 2] + sv2;
}

extern "C" void kernel_launch(void* const* d_in, const int* in_sizes, int n_in,
                              void* d_out, int out_size, void* d_ws, size_t ws_size,
                              hipStream_t stream) {
    (void)in_sizes; (void)n_in; (void)out_size; (void)ws_size;
    const float* node_attrs = (const float*)d_in[0];
    const float* node_feats = (const float*)d_in[1];
    const float* edge_attrs = (const float*)d_in[2];
    const float* edge_feats = (const float*)d_in[3];
    const int*   edge_index = (const int*)d_in[4];
    const float* Wgen = (const float*)d_in[5];
    const float* L1s  = (const float*)d_in[6];
    const float* L1v  = (const float*)d_in[7];
    const float* WS0  = (const float*)d_in[8];
    const float* WS1  = (const float*)d_in[9];
    const float* L2s  = (const float*)d_in[10];
    const float* L2v  = (const float*)d_in[11];
    float* out = (float*)d_out;

    char* ws = (char*)d_ws;
    float* Ms = (float*)ws;                                   // 10000*32*4  = 1,280,000
    float* Mv = (float*)(ws + 1280000);                       // 10000*96*4  = 3,840,000
    unsigned short* Wc = (unsigned short*)(ws + 5120000);     // 32768*2     = 65,536
    float* WS0p = (float*)(ws + 5185536);                     // 16384*4     = 65,536
    float* WS1p = (float*)(ws + 5251072);                     // 16384*4     = 65,536

    hipMemsetAsync(d_ws, 0, 5120000, stream);                 // zero Ms/Mv accumulators
    prep_kernel<<<256, 256, 0, stream>>>(Wgen, L1s, L1v, WS0, WS1, L2s, L2v,
                                         Wc, WS0p, WS1p);
    edge_kernel<<<512, 256, 0, stream>>>(node_feats, edge_attrs, edge_feats,
                                         edge_index, Wc, Ms, Mv);
    node_kernel<<<1250, 256, 0, stream>>>(node_attrs, Ms, Mv, WS0p, WS1p, out);
}

// Round 2
// 228.083 us; speedup vs baseline: 1.1004x; 1.1004x over previous
//
#include <hip/hip_runtime.h>
#include <hip/hip_bf16.h>

#define N_NODES 10000
#define N_EDGES 100000

typedef __attribute__((ext_vector_type(8))) short short8;
typedef __attribute__((ext_vector_type(4))) float f32x4;

static __device__ inline short bf16bits(float x) {
    union { __bf16 b; short s; } u;
    u.b = (__bf16)x;
    return u.s;
}
static __device__ inline unsigned short bf16u(float x) {
    union { __bf16 b; unsigned short s; } u;
    u.b = (__bf16)x;
    return u.s;
}
static __device__ inline float bf2f(unsigned short us) {
    union { unsigned int u; float f; } c;
    c.u = ((unsigned int)us) << 16;
    return c.f;
}

static __device__ inline short8 cvt8(const float* f) {
    short8 r;
#pragma unroll
    for (int j = 0; j < 8; ++j) r[j] = bf16bits(f[j]);
    return r;
}

// ---------------------------------------------------------------------------
// Precompute: fold L1s/L1v into Wgen (bf16, MFMA B-fragment order), fold
// L2s/L2v into WS0/WS1 (f32 [k][w]), and histogram edge receivers into deg.
// Edge combined scale: rnorm*alpha*lnorm = 1/128. Node: snorm*lnorm = 1/128.
// ---------------------------------------------------------------------------
__global__ __launch_bounds__(256) void prep_kernel(
    const float* __restrict__ Wgen, const float* __restrict__ L1s,
    const float* __restrict__ L1v, const float* __restrict__ WS0,
    const float* __restrict__ WS1, const float* __restrict__ L2s,
    const float* __restrict__ L2v, const int* __restrict__ edge_index,
    unsigned short* __restrict__ Wc, float* __restrict__ WS0p,
    float* __restrict__ WS1p, int* __restrict__ deg) {
    const float S = 1.0f / 128.0f;
    int tid = blockIdx.x * 256 + threadIdx.x;
    if (tid < 32768) {
        // B-fragment order: flat = ((nt*8 + ks)*64 + lane)*8 + j
        int j = tid & 7;
        int lane = (tid >> 3) & 63;
        int ks = (tid >> 9) & 7;
        int nt = tid >> 12;
        int col = nt * 16 + (lane & 15);
        int u = (lane >> 4) * 8 + j;
        int r = ks;
        int p, c2;
        const float* M;
        float sc = S;
        if (col < 32)      { p = 0; M = L1s; c2 = col; }
        else if (col < 64) { p = 1; M = L1v; c2 = col - 32; }
        else if (col < 96) { p = 2; M = L1v; c2 = col - 64; }
        else               { p = 3; M = L1s; c2 = col - 96; sc = S * 0.57735026918962576f; }
        const float* wg = Wgen + r * 4096 + p * 1024 + u * 32;
        float acc = 0.f;
#pragma unroll
        for (int w = 0; w < 32; ++w) acc += wg[w] * M[w * 32 + c2];
        Wc[tid] = bf16u(acc * sc);
    } else if (tid < 65536) {
        int idx = tid - 32768;
        int path = idx >> 14;
        int idx2 = idx & 16383;   // k*32 + w
        int k = idx2 >> 5;
        int w = idx2 & 31;
        int u = k >> 4, v = k & 15;
        const float* WS = path ? WS1 : WS0;
        const float* L2 = path ? L2v : L2s;
        const float* src = WS + u * 512 + v * 32;
        float acc = 0.f;
#pragma unroll
        for (int x = 0; x < 32; ++x) acc += src[x] * L2[x * 32 + w];
        float val = acc * S;
        if (path) WS1p[idx2] = val; else WS0p[idx2] = val;
    } else if (tid < 65536 + N_EDGES) {
        int e = tid - 65536;
        atomicAdd(&deg[edge_index[N_EDGES + e]], 1);
    }
}

// ---------------------------------------------------------------------------
// Exclusive scan over deg[10000] -> off[10001]; cursor = copy of off.
// Single block, 256 threads, 40 elements/thread.
// ---------------------------------------------------------------------------
__global__ __launch_bounds__(256) void scan_kernel(
    const int* __restrict__ deg, int* __restrict__ off, int* __restrict__ cursor) {
    __shared__ int part[256];
    int t = threadIdx.x;
    int base = t * 40;
    int s = 0;
    for (int i = 0; i < 40; ++i) {
        int idx = base + i;
        if (idx < N_NODES) s += deg[idx];
    }
    part[t] = s;
    __syncthreads();
    for (int d = 1; d < 256; d <<= 1) {
        int v = (t >= d) ? part[t - d] : 0;
        __syncthreads();
        part[t] += v;
        __syncthreads();
    }
    int run = part[t] - s;   // exclusive prefix of this chunk
    for (int i = 0; i < 40; ++i) {
        int idx = base + i;
        if (idx < N_NODES) {
            off[idx] = run;
            cursor[idx] = run;
            run += deg[idx];
        }
    }
    if (t == 255) off[N_NODES] = run;
}

__global__ __launch_bounds__(256) void slot_kernel(
    const int* __restrict__ edge_index, int* __restrict__ cursor,
    int* __restrict__ slot) {
    int e = blockIdx.x * 256 + threadIdx.x;
    if (e < N_EDGES) {
        int r = edge_index[N_EDGES + e];
        slot[e] = atomicAdd(&cursor[r], 1);
    }
}

// ---------------------------------------------------------------------------
// Edge kernel: per 16-edge tile (one wave), MFMA over K=256.
// MODE 0: store bf16 message to Msg[slot[e]] (CSR scatter, no atomics).
// MODE 1: fallback, f32 atomics into Ms/Mv.
// Msg row layout (128 x bf16): [ms(32) | mvx(32) | mvy(32) | mvz(32)]
// ---------------------------------------------------------------------------
template <int MODE>
__global__ __launch_bounds__(256) void edge_kernel(
    const float* __restrict__ node_feats, const float* __restrict__ edge_attrs,
    const float* __restrict__ edge_feats, const int* __restrict__ edge_index,
    const unsigned short* __restrict__ Wc, const int* __restrict__ slot,
    unsigned short* __restrict__ Msg, float* __restrict__ Ms,
    float* __restrict__ Mv) {
    __shared__ f32x4 sWv[4096];  // 64KB bf16 weights in B-fragment order
    {
        const f32x4* src = (const f32x4*)Wc;
        for (int i = threadIdx.x; i < 4096; i += 256) sWv[i] = src[i];
    }
    __syncthreads();
    const short8* sW8 = (const short8*)sWv;

    int lane = threadIdx.x & 63;
    int m = lane & 15, q = lane >> 4;
    int wave = (blockIdx.x * 256 + threadIdx.x) >> 6;
    int nwaves = gridDim.x * 4;

    for (int tile = wave; tile < N_EDGES / 16; tile += nwaves) {
        int e = tile * 16 + m;
        int snd = edge_index[e];
        int dst = (MODE == 0) ? slot[e] : edge_index[N_EDGES + e];
        const float* g = node_feats + snd * 128;

        float xs[8], xv[24], ef[8], dt[8];
        *(f32x4*)&xs[0] = *(const f32x4*)(g + q * 8);
        *(f32x4*)&xs[4] = *(const f32x4*)(g + q * 8 + 4);
#pragma unroll
        for (int i = 0; i < 6; ++i)
            *(f32x4*)&xv[i * 4] = *(const f32x4*)(g + 32 + q * 24 + i * 4);
        *(f32x4*)&ef[0] = *(const f32x4*)(edge_feats + e * 8);
        *(f32x4*)&ef[4] = *(const f32x4*)(edge_feats + e * 8 + 4);
        f32x4 ea = *(const f32x4*)(edge_attrs + e * 4);
        float ys = ea.x, yv0 = ea.y, yv1 = ea.z, yv2 = ea.w;
#pragma unroll
        for (int j = 0; j < 8; ++j)
            dt[j] = xv[j * 3] * yv0 + xv[j * 3 + 1] * yv1 + xv[j * 3 + 2] * yv2;

        f32x4 z = {0.f, 0.f, 0.f, 0.f};
        f32x4 fA[2] = {z, z}, fB[2] = {z, z}, fD[2] = {z, z};
        f32x4 fC[3][2] = {{z, z}, {z, z}, {z, z}};

#pragma unroll
        for (int ks = 0; ks < 8; ++ks) {
            float h = ef[ks];
            float t0[8], t1[8], t2[8], t3[8], t4[8];
#pragma unroll
            for (int j = 0; j < 8; ++j) {
                t0[j] = h * xs[j];
                t1[j] = h * xv[j * 3 + 0];
                t2[j] = h * xv[j * 3 + 1];
                t3[j] = h * xv[j * 3 + 2];
                t4[j] = h * dt[j];
            }
            short8 a_xs = cvt8(t0);
            short8 a_v0 = cvt8(t1);
            short8 a_v1 = cvt8(t2);
            short8 a_v2 = cvt8(t3);
            short8 a_d  = cvt8(t4);
#define BFRAG(nt) sW8[((nt) * 8 + ks) * 64 + lane]
            fA[0] = __builtin_amdgcn_mfma_f32_16x16x32_bf16(a_xs, BFRAG(0), fA[0], 0, 0, 0);
            fA[1] = __builtin_amdgcn_mfma_f32_16x16x32_bf16(a_xs, BFRAG(1), fA[1], 0, 0, 0);
            fB[0] = __builtin_amdgcn_mfma_f32_16x16x32_bf16(a_xs, BFRAG(2), fB[0], 0, 0, 0);
            fB[1] = __builtin_amdgcn_mfma_f32_16x16x32_bf16(a_xs, BFRAG(3), fB[1], 0, 0, 0);
            short8 bc0 = BFRAG(4), bc1 = BFRAG(5);
            fC[0][0] = __builtin_amdgcn_mfma_f32_16x16x32_bf16(a_v0, bc0, fC[0][0], 0, 0, 0);
            fC[0][1] = __builtin_amdgcn_mfma_f32_16x16x32_bf16(a_v0, bc1, fC[0][1], 0, 0, 0);
            fC[1][0] = __builtin_amdgcn_mfma_f32_16x16x32_bf16(a_v1, bc0, fC[1][0], 0, 0, 0);
            fC[1][1] = __builtin_amdgcn_mfma_f32_16x16x32_bf16(a_v1, bc1, fC[1][1], 0, 0, 0);
            fC[2][0] = __builtin_amdgcn_mfma_f32_16x16x32_bf16(a_v2, bc0, fC[2][0], 0, 0, 0);
            fC[2][1] = __builtin_amdgcn_mfma_f32_16x16x32_bf16(a_v2, bc1, fC[2][1], 0, 0, 0);
            fD[0] = __builtin_amdgcn_mfma_f32_16x16x32_bf16(a_d, BFRAG(6), fD[0], 0, 0, 0);
            fD[1] = __builtin_amdgcn_mfma_f32_16x16x32_bf16(a_d, BFRAG(7), fD[1], 0, 0, 0);
#undef BFRAG
        }

        // Epilogue: D-frag row = q*4+t (edge in tile), col = m (+16*nt)
#pragma unroll
        for (int t = 0; t < 4; ++t) {
            int row = q * 4 + t;
            float ysr = __shfl(ys, row);
            float y0r = __shfl(yv0, row);
            float y1r = __shfl(yv1, row);
            float y2r = __shfl(yv2, row);
            int dr = __shfl(dst, row);
#pragma unroll
            for (int nt = 0; nt < 2; ++nt) {
                int col = nt * 16 + m;
                float vms = ysr * fA[nt][t] + fD[nt][t];
                float pb = fB[nt][t];
                float v0 = y0r * pb + ysr * fC[0][nt][t];
                float v1 = y1r * pb + ysr * fC[1][nt][t];
                float v2 = y2r * pb + ysr * fC[2][nt][t];
                if (MODE == 0) {
                    int sb = dr * 128;
                    Msg[sb + col] = bf16u(vms);
                    Msg[sb + 32 + col] = bf16u(v0);
                    Msg[sb + 64 + col] = bf16u(v1);
                    Msg[sb + 96 + col] = bf16u(v2);
                } else {
                    unsafeAtomicAdd(&Ms[dr * 32 + col], vms);
                    unsafeAtomicAdd(&Mv[dr * 96 + col * 3 + 0], v0);
                    unsafeAtomicAdd(&Mv[dr * 96 + col * 3 + 1], v1);
                    unsafeAtomicAdd(&Mv[dr * 96 + col * 3 + 2], v2);
                }
            }
        }
    }
}

// ---------------------------------------------------------------------------
// Gather: node n sums its contiguous CSR message rows into Ms/Mv (f32).
// 2 nodes per 256-block, 128 threads (one channel each).
// ---------------------------------------------------------------------------
__global__ __launch_bounds__(256) void gather_kernel(
    const unsigned short* __restrict__ Msg, const int* __restrict__ off,
    float* __restrict__ Ms, float* __restrict__ Mv) {
    int n = blockIdx.x * 2 + (threadIdx.x >> 7);
    int c = threadIdx.x & 127;
    int s0 = off[n], s1 = off[n + 1];
    float acc = 0.f;
    for (int s = s0; s < s1; ++s) acc += bf2f(Msg[s * 128 + c]);
    if (c < 32) {
        Ms[n * 32 + c] = acc;
    } else {
        int comp = (c >> 5) - 1;
        int u = c & 31;
        Mv[n * 96 + u * 3 + comp] = acc;
    }
}

// ---------------------------------------------------------------------------
// Node kernel (unchanged from R1): skip-connection contraction.
// ---------------------------------------------------------------------------
__global__ __launch_bounds__(256) void node_kernel(
    const float* __restrict__ node_attrs, const float* __restrict__ Ms,
    const float* __restrict__ Mv, const float* __restrict__ WS0p,
    const float* __restrict__ WS1p, float* __restrict__ out) {
    __shared__ float sMs[8][32], sMv[8][96], sAt[8][16];
    int slot = threadIdx.x >> 5, w = threadIdx.x & 31;
    int n = blockIdx.x * 8 + slot;
    sMs[slot][w] = Ms[n * 32 + w];
    sMv[slot][w] = Mv[n * 96 + w];
    sMv[slot][32 + w] = Mv[n * 96 + 32 + w];
    sMv[slot][64 + w] = Mv[n * 96 + 64 + w];
    if (w < 16) sAt[slot][w] = node_attrs[n * 16 + w];
    __syncthreads();

    float ss = 0.f, sv0 = 0.f, sv1 = 0.f, sv2 = 0.f;
    for (int u = 0; u < 32; ++u) {
        float msu = sMs[slot][u];
        float m0 = sMv[slot][u * 3 + 0];
        float m1 = sMv[slot][u * 3 + 1];
        float m2 = sMv[slot][u * 3 + 2];
        const float* w0p = WS0p + u * 512 + w;
        const float* w1p = WS1p + u * 512 + w;
#pragma unroll
        for (int v = 0; v < 16; ++v) {
            float av = sAt[slot][v];
            float wt0 = w0p[v * 32];
            float wt1 = w1p[v * 32];
            ss  += (msu * av) * wt0;
            sv0 += (m0 * av) * wt1;
            sv1 += (m1 * av) * wt1;
            sv2 += (m2 * av) * wt1;
        }
    }
    out[n * 128 + w] = sMs[slot][w] + ss;
    out[n * 128 + 32 + w * 3 + 0] = sMv[slot][w * 3 + 0] + sv0;
    out[n * 128 + 32 + w * 3 + 1] = sMv[slot][w * 3 + 1] + sv1;
    out[n * 128 + 32 + w * 3 + 2] = sMv[slot][w * 3 + 2] + sv2;
}

extern "C" void kernel_launch(void* const* d_in, const int* in_sizes, int n_in,
                              void* d_out, int out_size, void* d_ws, size_t ws_size,
                              hipStream_t stream) {
    (void)in_sizes; (void)n_in; (void)out_size;
    const float* node_attrs = (const float*)d_in[0];
    const float* node_feats = (const float*)d_in[1];
    const float* edge_attrs = (const float*)d_in[2];
    const float* edge_feats = (const float*)d_in[3];
    const int*   edge_index = (const int*)d_in[4];
    const float* Wgen = (const float*)d_in[5];
    const float* L1s  = (const float*)d_in[6];
    const float* L1v  = (const float*)d_in[7];
    const float* WS0  = (const float*)d_in[8];
    const float* WS1  = (const float*)d_in[9];
    const float* L2s  = (const float*)d_in[10];
    const float* L2v  = (const float*)d_in[11];
    float* out = (float*)d_out;
    char* ws = (char*)d_ws;

    const size_t NEED = 31500000;
    if (ws_size >= NEED) {
        // CSR scatter/gather path (no f32 atomics)
        unsigned short* Msg = (unsigned short*)ws;                 // 25,600,000
        float* Ms   = (float*)(ws + 25600000);                     //  1,280,000
        float* Mv   = (float*)(ws + 26880000);                     //  3,840,000
        unsigned short* Wc = (unsigned short*)(ws + 30720000);     //     65,536
        float* WS0p = (float*)(ws + 30785536);                     //     65,536
        float* WS1p = (float*)(ws + 30851072);                     //     65,536
        int* deg    = (int*)(ws + 30916608);                       //     40,000
        int* off    = (int*)(ws + 30956608);                       //     40,008
        int* cursor = (int*)(ws + 30996616);                       //     40,000
        int* slot   = (int*)(ws + 31036616);                       //    400,000

        hipMemsetAsync(deg, 0, 40000, stream);
        prep_kernel<<<647, 256, 0, stream>>>(Wgen, L1s, L1v, WS0, WS1, L2s, L2v,
                                             edge_index, Wc, WS0p, WS1p, deg);
        scan_kernel<<<1, 256, 0, stream>>>(deg, off, cursor);
        slot_kernel<<<391, 256, 0, stream>>>(edge_index, cursor, slot);
        edge_kernel<0><<<512, 256, 0, stream>>>(node_feats, edge_attrs, edge_feats,
                                                edge_index, Wc, slot, Msg, Ms, Mv);
        gather_kernel<<<5000, 256, 0, stream>>>(Msg, off, Ms, Mv);
        node_kernel<<<1250, 256, 0, stream>>>(node_attrs, Ms, Mv, WS0p, WS1p, out);
    } else {
        // Fallback: R1 atomic path
        float* Ms = (float*)ws;                                    //  1,280,000
        float* Mv = (float*)(ws + 1280000);                        //  3,840,000
        unsigned short* Wc = (unsigned short*)(ws + 5120000);      //     65,536
        float* WS0p = (float*)(ws + 5185536);                      //     65,536
        float* WS1p = (float*)(ws + 5251072);                      //     65,536
        int* deg    = (int*)(ws + 5316608);                        //     40,000 (hist scratch)

        hipMemsetAsync(ws, 0, 5120000, stream);
        hipMemsetAsync(deg, 0, 40000, stream);
        prep_kernel<<<647, 256, 0, stream>>>(Wgen, L1s, L1v, WS0, WS1, L2s, L2v,
                                             edge_index, Wc, WS0p, WS1p, deg);
        edge_kernel<1><<<512, 256, 0, stream>>>(node_feats, edge_attrs, edge_feats,
                                                edge_index, Wc, nullptr, nullptr, Ms, Mv);
        node_kernel<<<1250, 256, 0, stream>>>(node_attrs, Ms, Mv, WS0p, WS1p, out);
    }
}

// Round 3
// 180.214 us; speedup vs baseline: 1.3927x; 1.2656x over previous
//
#include <hip/hip_runtime.h>
#include <hip/hip_bf16.h>

#define N_NODES 10000
#define N_EDGES 100000

typedef __attribute__((ext_vector_type(8))) short short8;
typedef __attribute__((ext_vector_type(4))) float f32x4;

static __device__ inline short bf16bits(float x) {
    union { __bf16 b; short s; } u;
    u.b = (__bf16)x;
    return u.s;
}
static __device__ inline unsigned short bf16u(float x) {
    union { __bf16 b; unsigned short s; } u;
    u.b = (__bf16)x;
    return u.s;
}
static __device__ inline float bf2f(unsigned short us) {
    union { unsigned int u; float f; } c;
    c.u = ((unsigned int)us) << 16;
    return c.f;
}
static __device__ inline short8 cvt8(const float* f) {
    short8 r;
#pragma unroll
    for (int j = 0; j < 8; ++j) r[j] = bf16bits(f[j]);
    return r;
}

// ---------------------------------------------------------------------------
// Precompute:
//  [0,32768):      fold L1s/L1v into Wgen -> Wc (bf16, MFMA B-frag order)
//  [32768,65536):  fold L2s/L2v into WS0/WS1 -> WB0/WB1 (bf16, B-frag order,
//                  K=512: ks 0..15, nt 0..1)
//  [65536,165536): histogram edge receivers into deg
// Edge scale: rnorm*alpha*lnorm = 1/128. Node scale: snorm*lnorm = 1/128.
// ---------------------------------------------------------------------------
__global__ __launch_bounds__(256) void prep_kernel(
    const float* __restrict__ Wgen, const float* __restrict__ L1s,
    const float* __restrict__ L1v, const float* __restrict__ WS0,
    const float* __restrict__ WS1, const float* __restrict__ L2s,
    const float* __restrict__ L2v, const int* __restrict__ edge_index,
    unsigned short* __restrict__ Wc, unsigned short* __restrict__ WB0,
    unsigned short* __restrict__ WB1, int* __restrict__ deg) {
    const float S = 1.0f / 128.0f;
    int tid = blockIdx.x * 256 + threadIdx.x;
    if (tid < 32768) {
        // flat = ((nt*8 + ks)*64 + lane)*8 + j
        int j = tid & 7;
        int lane = (tid >> 3) & 63;
        int ks = (tid >> 9) & 7;
        int nt = tid >> 12;
        int col = nt * 16 + (lane & 15);
        int u = (lane >> 4) * 8 + j;
        int r = ks;
        int p, c2;
        const float* M;
        float sc = S;
        if (col < 32)      { p = 0; M = L1s; c2 = col; }
        else if (col < 64) { p = 1; M = L1v; c2 = col - 32; }
        else if (col < 96) { p = 2; M = L1v; c2 = col - 64; }
        else               { p = 3; M = L1s; c2 = col - 96; sc = S * 0.57735026918962576f; }
        const float* wg = Wgen + r * 4096 + p * 1024 + u * 32;
        float acc = 0.f;
#pragma unroll
        for (int w = 0; w < 32; ++w) acc += wg[w] * M[w * 32 + c2];
        Wc[tid] = bf16u(acc * sc);
    } else if (tid < 65536) {
        int idx = tid - 32768;
        int table = idx >> 14;
        int r14 = idx & 16383;          // ((nt*16+ks)*64+lane)*8+j
        int j = r14 & 7;
        int lane = (r14 >> 3) & 63;
        int ks = (r14 >> 9) & 15;
        int k = ks * 32 + (lane >> 4) * 8 + j;   // 0..511
        int u = k >> 4, v = k & 15;
        int w = ((r14 >> 13) & 1) * 16 + (lane & 15);
        const float* WS = table ? WS1 : WS0;
        const float* L2 = table ? L2v : L2s;
        const float* src = WS + u * 512 + v * 32;
        float acc = 0.f;
#pragma unroll
        for (int x = 0; x < 32; ++x) acc += src[x] * L2[x * 32 + w];
        unsigned short val = bf16u(acc * S);
        if (table) WB1[r14] = val; else WB0[r14] = val;
    } else if (tid < 65536 + N_EDGES) {
        int e = tid - 65536;
        atomicAdd(&deg[edge_index[N_EDGES + e]], 1);
    }
}

// ---------------------------------------------------------------------------
// Exclusive scan over deg[10000] -> off[10001]; cursor = copy of off.
// ---------------------------------------------------------------------------
__global__ __launch_bounds__(256) void scan_kernel(
    const int* __restrict__ deg, int* __restrict__ off, int* __restrict__ cursor) {
    __shared__ int part[256];
    int t = threadIdx.x;
    int base = t * 40;
    int s = 0;
    for (int i = 0; i < 40; ++i) {
        int idx = base + i;
        if (idx < N_NODES) s += deg[idx];
    }
    part[t] = s;
    __syncthreads();
    for (int d = 1; d < 256; d <<= 1) {
        int v = (t >= d) ? part[t - d] : 0;
        __syncthreads();
        part[t] += v;
        __syncthreads();
    }
    int run = part[t] - s;
    for (int i = 0; i < 40; ++i) {
        int idx = base + i;
        if (idx < N_NODES) {
            off[idx] = run;
            cursor[idx] = run;
            run += deg[idx];
        }
    }
    if (t == 255) off[N_NODES] = run;
}

__global__ __launch_bounds__(256) void slot_kernel(
    const int* __restrict__ edge_index, int* __restrict__ cursor,
    int* __restrict__ slot) {
    int e = blockIdx.x * 256 + threadIdx.x;
    if (e < N_EDGES) {
        int r = edge_index[N_EDGES + e];
        slot[e] = atomicAdd(&cursor[r], 1);
    }
}

// ---------------------------------------------------------------------------
// Edge kernel: 16-edge tile per wave, MFMA over K=256, bf16 message store to
// Msg[slot[e]]. Msg row (128 bf16): [ms(32) | mvx(32) | mvy(32) | mvz(32)]
// ---------------------------------------------------------------------------
__global__ __launch_bounds__(256) void edge_kernel(
    const float* __restrict__ node_feats, const float* __restrict__ edge_attrs,
    const float* __restrict__ edge_feats, const int* __restrict__ edge_index,
    const unsigned short* __restrict__ Wc, const int* __restrict__ slot,
    unsigned short* __restrict__ Msg) {
    __shared__ f32x4 sWv[4096];  // 64KB bf16 weights in B-fragment order
    {
        const f32x4* src = (const f32x4*)Wc;
        for (int i = threadIdx.x; i < 4096; i += 256) sWv[i] = src[i];
    }
    __syncthreads();
    const short8* sW8 = (const short8*)sWv;

    int lane = threadIdx.x & 63;
    int m = lane & 15, q = lane >> 4;
    int wave = (blockIdx.x * 256 + threadIdx.x) >> 6;
    int nwaves = gridDim.x * 4;

    for (int tile = wave; tile < N_EDGES / 16; tile += nwaves) {
        int e = tile * 16 + m;
        int snd = edge_index[e];
        int dst = slot[e];
        const float* g = node_feats + snd * 128;

        float xs[8], xv[24], ef[8], dt[8];
        *(f32x4*)&xs[0] = *(const f32x4*)(g + q * 8);
        *(f32x4*)&xs[4] = *(const f32x4*)(g + q * 8 + 4);
#pragma unroll
        for (int i = 0; i < 6; ++i)
            *(f32x4*)&xv[i * 4] = *(const f32x4*)(g + 32 + q * 24 + i * 4);
        *(f32x4*)&ef[0] = *(const f32x4*)(edge_feats + e * 8);
        *(f32x4*)&ef[4] = *(const f32x4*)(edge_feats + e * 8 + 4);
        f32x4 ea = *(const f32x4*)(edge_attrs + e * 4);
        float ys = ea.x, yv0 = ea.y, yv1 = ea.z, yv2 = ea.w;
#pragma unroll
        for (int j = 0; j < 8; ++j)
            dt[j] = xv[j * 3] * yv0 + xv[j * 3 + 1] * yv1 + xv[j * 3 + 2] * yv2;

        f32x4 z = {0.f, 0.f, 0.f, 0.f};
        f32x4 fA[2] = {z, z}, fB[2] = {z, z}, fD[2] = {z, z};
        f32x4 fC[3][2] = {{z, z}, {z, z}, {z, z}};

#pragma unroll
        for (int ks = 0; ks < 8; ++ks) {
            float h = ef[ks];
            float t0[8], t1[8], t2[8], t3[8], t4[8];
#pragma unroll
            for (int j = 0; j < 8; ++j) {
                t0[j] = h * xs[j];
                t1[j] = h * xv[j * 3 + 0];
                t2[j] = h * xv[j * 3 + 1];
                t3[j] = h * xv[j * 3 + 2];
                t4[j] = h * dt[j];
            }
            short8 a_xs = cvt8(t0);
            short8 a_v0 = cvt8(t1);
            short8 a_v1 = cvt8(t2);
            short8 a_v2 = cvt8(t3);
            short8 a_d  = cvt8(t4);
#define BFRAG(nt) sW8[((nt) * 8 + ks) * 64 + lane]
            fA[0] = __builtin_amdgcn_mfma_f32_16x16x32_bf16(a_xs, BFRAG(0), fA[0], 0, 0, 0);
            fA[1] = __builtin_amdgcn_mfma_f32_16x16x32_bf16(a_xs, BFRAG(1), fA[1], 0, 0, 0);
            fB[0] = __builtin_amdgcn_mfma_f32_16x16x32_bf16(a_xs, BFRAG(2), fB[0], 0, 0, 0);
            fB[1] = __builtin_amdgcn_mfma_f32_16x16x32_bf16(a_xs, BFRAG(3), fB[1], 0, 0, 0);
            short8 bc0 = BFRAG(4), bc1 = BFRAG(5);
            fC[0][0] = __builtin_amdgcn_mfma_f32_16x16x32_bf16(a_v0, bc0, fC[0][0], 0, 0, 0);
            fC[0][1] = __builtin_amdgcn_mfma_f32_16x16x32_bf16(a_v0, bc1, fC[0][1], 0, 0, 0);
            fC[1][0] = __builtin_amdgcn_mfma_f32_16x16x32_bf16(a_v1, bc0, fC[1][0], 0, 0, 0);
            fC[1][1] = __builtin_amdgcn_mfma_f32_16x16x32_bf16(a_v1, bc1, fC[1][1], 0, 0, 0);
            fC[2][0] = __builtin_amdgcn_mfma_f32_16x16x32_bf16(a_v2, bc0, fC[2][0], 0, 0, 0);
            fC[2][1] = __builtin_amdgcn_mfma_f32_16x16x32_bf16(a_v2, bc1, fC[2][1], 0, 0, 0);
            fD[0] = __builtin_amdgcn_mfma_f32_16x16x32_bf16(a_d, BFRAG(6), fD[0], 0, 0, 0);
            fD[1] = __builtin_amdgcn_mfma_f32_16x16x32_bf16(a_d, BFRAG(7), fD[1], 0, 0, 0);
#undef BFRAG
        }

#pragma unroll
        for (int t = 0; t < 4; ++t) {
            int row = q * 4 + t;
            float ysr = __shfl(ys, row);
            float y0r = __shfl(yv0, row);
            float y1r = __shfl(yv1, row);
            float y2r = __shfl(yv2, row);
            int dr = __shfl(dst, row);
#pragma unroll
            for (int nt = 0; nt < 2; ++nt) {
                int col = nt * 16 + m;
                int sb = dr * 128;
                Msg[sb + col]      = bf16u(ysr * fA[nt][t] + fD[nt][t]);
                float pb = fB[nt][t];
                Msg[sb + 32 + col] = bf16u(y0r * pb + ysr * fC[0][nt][t]);
                Msg[sb + 64 + col] = bf16u(y1r * pb + ysr * fC[1][nt][t]);
                Msg[sb + 96 + col] = bf16u(y2r * pb + ysr * fC[2][nt][t]);
            }
        }
    }
}

// ---------------------------------------------------------------------------
// Fused gather + node kernel. Block = 16 nodes, 256 threads.
// Phase 1: gather CSR rows (16B loads) -> LDS f32 sM[16][129] (+1 pad).
// Phase 2: wave p computes path p (p0: ss vs WB0; p1-3: sv_i vs WB1) as a
//          16x32x512 MFMA GEMM; A[n][k] = sM[n][p*32 + (k>>4)] * sAt[n][k&15].
// Epilogue: out = skip(sM, f32) + D.
// ---------------------------------------------------------------------------
__global__ __launch_bounds__(256) void node_kernel(
    const float* __restrict__ node_attrs, const unsigned short* __restrict__ Msg,
    const int* __restrict__ off, const unsigned short* __restrict__ WB0,
    const unsigned short* __restrict__ WB1, float* __restrict__ out) {
    __shared__ float sM[16][129];
    __shared__ float sAt[16][17];
    int n0 = blockIdx.x * 16;

    // Phase 1: 16 threads per node, each owns 8 channels
    int nl = threadIdx.x >> 4;
    int cg = threadIdx.x & 15;
    int n = n0 + nl;
    int s0 = off[n], s1 = off[n + 1];
    float acc[8];
#pragma unroll
    for (int j = 0; j < 8; ++j) acc[j] = 0.f;
    for (int s = s0; s < s1; ++s) {
        f32x4 raw = *(const f32x4*)(Msg + s * 128 + cg * 8);
        const unsigned short* us = (const unsigned short*)&raw;
#pragma unroll
        for (int j = 0; j < 8; ++j) acc[j] += bf2f(us[j]);
    }
#pragma unroll
    for (int j = 0; j < 8; ++j) sM[nl][cg * 8 + j] = acc[j];
    sAt[nl][cg] = node_attrs[n * 16 + cg];
    __syncthreads();

    // Phase 2
    int p = threadIdx.x >> 6;
    int lane = threadIdx.x & 63;
    int m = lane & 15, q = lane >> 4;
    const unsigned short* WB = (p == 0) ? WB0 : WB1;
    int chb = p * 32;
    f32x4 z = {0.f, 0.f, 0.f, 0.f};
    f32x4 D0 = z, D1 = z;
#pragma unroll
    for (int ks = 0; ks < 16; ++ks) {
        int kb = ks * 32 + q * 8;
        float t[8];
#pragma unroll
        for (int j = 0; j < 8; ++j) {
            int k = kb + j;
            t[j] = sM[m][chb + (k >> 4)] * sAt[m][k & 15];
        }
        short8 a = cvt8(t);
        short8 b0 = *(const short8*)(WB + (ks * 64 + lane) * 8);
        short8 b1 = *(const short8*)(WB + ((16 + ks) * 64 + lane) * 8);
        D0 = __builtin_amdgcn_mfma_f32_16x16x32_bf16(a, b0, D0, 0, 0, 0);
        D1 = __builtin_amdgcn_mfma_f32_16x16x32_bf16(a, b1, D1, 0, 0, 0);
    }

    // Epilogue: D row = q*4+t4 (node-local), col = m (+16 for D1)
#pragma unroll
    for (int t4 = 0; t4 < 4; ++t4) {
        int nl2 = q * 4 + t4;
        int nn = n0 + nl2;
        if (p == 0) {
            out[nn * 128 + m]      = sM[nl2][m] + D0[t4];
            out[nn * 128 + 16 + m] = sM[nl2][16 + m] + D1[t4];
        } else {
            int i = p - 1;
            out[nn * 128 + 32 + m * 3 + i]        = sM[nl2][chb + m] + D0[t4];
            out[nn * 128 + 32 + (16 + m) * 3 + i] = sM[nl2][chb + 16 + m] + D1[t4];
        }
    }
}

extern "C" void kernel_launch(void* const* d_in, const int* in_sizes, int n_in,
                              void* d_out, int out_size, void* d_ws, size_t ws_size,
                              hipStream_t stream) {
    (void)in_sizes; (void)n_in; (void)out_size; (void)ws_size;
    const float* node_attrs = (const float*)d_in[0];
    const float* node_feats = (const float*)d_in[1];
    const float* edge_attrs = (const float*)d_in[2];
    const float* edge_feats = (const float*)d_in[3];
    const int*   edge_index = (const int*)d_in[4];
    const float* Wgen = (const float*)d_in[5];
    const float* L1s  = (const float*)d_in[6];
    const float* L1v  = (const float*)d_in[7];
    const float* WS0  = (const float*)d_in[8];
    const float* WS1  = (const float*)d_in[9];
    const float* L2s  = (const float*)d_in[10];
    const float* L2v  = (const float*)d_in[11];
    float* out = (float*)d_out;
    char* ws = (char*)d_ws;

    unsigned short* Msg = (unsigned short*)ws;                 // 25,600,000
    unsigned short* Wc  = (unsigned short*)(ws + 25600000);    //     65,536
    unsigned short* WB0 = (unsigned short*)(ws + 25665536);    //     32,768
    unsigned short* WB1 = (unsigned short*)(ws + 25698304);    //     32,768
    int* deg    = (int*)(ws + 25731072);                       //     40,000
    int* off    = (int*)(ws + 25771072);                       //     40,004
    int* cursor = (int*)(ws + 25811080);                       //     40,000
    int* slot   = (int*)(ws + 25851080);                       //    400,000

    hipMemsetAsync(deg, 0, 40000, stream);
    prep_kernel<<<647, 256, 0, stream>>>(Wgen, L1s, L1v, WS0, WS1, L2s, L2v,
                                         edge_index, Wc, WB0, WB1, deg);
    scan_kernel<<<1, 256, 0, stream>>>(deg, off, cursor);
    slot_kernel<<<391, 256, 0, stream>>>(edge_index, cursor, slot);
    edge_kernel<<<512, 256, 0, stream>>>(node_feats, edge_attrs, edge_feats,
                                         edge_index, Wc, slot, Msg);
    node_kernel<<<625, 256, 0, stream>>>(node_attrs, Msg, off, WB0, WB1, out);
}